// Round 3
// baseline (20.491 us; speedup 1.0000x reference)
//
#include <hip/hip_runtime.h>

// GNFConverter: per (b,p) point, per-type softmax over atoms of -dist logits,
// weighted sum of (coord - query) diffs, clipped to magnitude 0.3.
// Shapes fixed: B=8, A=128, P=8192, T=5.
//
// Strategy: atom data is block-uniform -> read it via SCALAR loads (s_load)
// and dispatch the atom's type with SCALAR branches (switch on an SGPR).
// The vector path per atom is then only ~12 VALU + 2 trans ops, with no LDS
// and no per-type predication. readfirstlane(tid>>6) makes wave id provably
// uniform so the compiler's divergence analysis allows s_load / s_cbranch.
// Each 64-point group is handled by a wave PAIR splitting the 128 atoms
// (64 each) for 2 waves/SIMD occupancy; partials merge via LDS (stride-21
// padding -> conflict-free), epilogue split by type between the two waves.

#define B_DIM 8
#define A_DIM 128
#define P_DIM 8192
#define NT 5

__global__ __launch_bounds__(256) void gnf_kernel(
    const float* __restrict__ coords,     // (B, A, 3) f32
    const int*   __restrict__ atom_types, // (B, A) i32
    const float* __restrict__ query,      // (B, P, 3) f32
    float*       __restrict__ out)        // (B, P, 5, 3) f32
{
    // partials: [wave][lane][20 used, 21 stride for bank-conflict-free]
    __shared__ float part[4][64][21];

    const int tid  = threadIdx.x;
    const int lane = tid & 63;
    // Force wave id into an SGPR so atom loads/branches are provably uniform.
    const int wid  = __builtin_amdgcn_readfirstlane(tid >> 6);
    const int half = wid & 1;   // which 64-atom half this wave reduces
    const int pair = wid >> 1;  // which 64-point group this wave serves

    const int blocks_per_b = P_DIM / 128;          // 64
    const int b  = blockIdx.x / blocks_per_b;
    const int p0 = (blockIdx.x % blocks_per_b) * 128;
    const int p  = p0 + pair * 64 + lane;

    const float* q = query + (size_t)(b * P_DIM + p) * 3;
    const float qx = q[0], qy = q[1], qz = q[2];

    float s[NT], gx[NT], gy[NT], gz[NT];
#pragma unroll
    for (int t = 0; t < NT; ++t) { s[t] = 0.f; gx[t] = 0.f; gy[t] = 0.f; gz[t] = 0.f; }

    // ---- hot loop: 64 atoms, all operands scalar (SGPR) except the point ----
    const int abase = b * A_DIM + half * 64;      // uniform
    const float* cb = coords + (size_t)abase * 3; // uniform base -> s_load
    const int*   tb = atom_types + abase;         // uniform base -> s_load
#pragma unroll 16
    for (int a = 0; a < 64; ++a) {
        const float ax = cb[a * 3 + 0];
        const float ay = cb[a * 3 + 1];
        const float az = cb[a * 3 + 2];
        const int   t  = tb[a];                   // SGPR -> scalar switch
        const float dx = ax - qx;
        const float dy = ay - qy;
        const float dz = az - qz;
        const float d2 = fmaf(dx, dx, fmaf(dy, dy, dz * dz));
        const float e  = __builtin_amdgcn_exp2f(
            __builtin_amdgcn_sqrtf(d2) * -1.44269504088896340736f); // exp(-dist)
        switch (t) {
        case 0: s[0]+=e; gx[0]=fmaf(e,dx,gx[0]); gy[0]=fmaf(e,dy,gy[0]); gz[0]=fmaf(e,dz,gz[0]); break;
        case 1: s[1]+=e; gx[1]=fmaf(e,dx,gx[1]); gy[1]=fmaf(e,dy,gy[1]); gz[1]=fmaf(e,dz,gz[1]); break;
        case 2: s[2]+=e; gx[2]=fmaf(e,dx,gx[2]); gy[2]=fmaf(e,dy,gy[2]); gz[2]=fmaf(e,dz,gz[2]); break;
        case 3: s[3]+=e; gx[3]=fmaf(e,dx,gx[3]); gy[3]=fmaf(e,dy,gy[3]); gz[3]=fmaf(e,dz,gz[3]); break;
        case 4: s[4]+=e; gx[4]=fmaf(e,dx,gx[4]); gy[4]=fmaf(e,dy,gy[4]); gz[4]=fmaf(e,dz,gz[4]); break;
        default: break;  // PADDING_INDEX: contributes nothing
        }
    }

    // ---- exchange partials between the two waves of the pair ----
#pragma unroll
    for (int t = 0; t < NT; ++t) {
        part[wid][lane][t * 4 + 0] = s[t];
        part[wid][lane][t * 4 + 1] = gx[t];
        part[wid][lane][t * 4 + 2] = gy[t];
        part[wid][lane][t * 4 + 3] = gz[t];
    }
    __syncthreads();

    // epilogue split by type: half 0 -> types {0,1}, half 1 -> types {2,3,4}
    const int ow = wid ^ 1;
    const int t_begin = half ? 2 : 0;
    const int t_end   = half ? NT : 2;
    float* o = out + (size_t)(b * P_DIM + p) * (NT * 3);
#pragma unroll
    for (int t = 0; t < NT; ++t) {
        if (t >= t_begin && t < t_end) {          // uniform -> scalar branch
            const float st = s[t]  + part[ow][lane][t * 4 + 0];
            float x        = gx[t] + part[ow][lane][t * 4 + 1];
            float y        = gy[t] + part[ow][lane][t * 4 + 2];
            float z        = gz[t] + part[ow][lane][t * 4 + 3];
            const float inv = (st > 0.f) ? (1.0f / st) : 0.0f;
            x *= inv; y *= inv; z *= inv;
            const float mag = __builtin_amdgcn_sqrtf(fmaf(x, x, fmaf(y, y, z * z)));
            if (mag > 0.3f) {
                const float sc = 0.3f / mag;
                x *= sc; y *= sc; z *= sc;
            }
            o[t * 3 + 0] = x;
            o[t * 3 + 1] = y;
            o[t * 3 + 2] = z;
        }
    }
}

extern "C" void kernel_launch(void* const* d_in, const int* in_sizes, int n_in,
                              void* d_out, int out_size, void* d_ws, size_t ws_size,
                              hipStream_t stream) {
    const float* coords     = (const float*)d_in[0];
    const int*   atom_types = (const int*)d_in[1];
    const float* query      = (const float*)d_in[2];
    float*       out        = (float*)d_out;

    // 512 blocks: each handles 128 points via 2 wave-pairs (atoms split 64/64).
    const int nblocks = (B_DIM * P_DIM) / 128;
    gnf_kernel<<<nblocks, 256, 0, stream>>>(coords, atom_types, query, out);
}

// Round 4
// 15.546 us; speedup vs baseline: 1.3181x; 1.3181x over previous
//
#include <hip/hip_runtime.h>

// GNFConverter: per (b,p) point, per-type softmax over atoms of -dist logits,
// weighted sum of (coord - query) diffs, clipped to magnitude 0.3.
// Shapes fixed: B=8, A=128, P=8192, T=5.
//
// Structure (best known = R2 + occupancy/ILP fixes):
//   - count-sort atoms by type into LDS segments once per block
//   - each point handled by an 8-lane group (KSPLIT=8); inner loops run
//     type-by-type over sorted segments: 4 accumulators, no predication
//   - 2048 blocks -> 8 waves/SIMD so ds_read+chain latency (~180cy/iter,
//     ~46cy issue) is fully hidden by TLP
//   - butterfly (xor 1,2,4) reduce within the 8-lane group; lane k==t
//     normalizes+clips type t (5-way lane-parallel epilogue), lanes 0..4
//     store 3 dwords each
//   - raw v_rcp/v_rsq/v_exp instructions; clip compare on mag^2

#define B_DIM 8
#define A_DIM 128
#define P_DIM 8192
#define NT 5
#define KSPLIT 8
#define PTS_PER_BLOCK 32   // 256 threads / KSPLIT

__global__ __launch_bounds__(256) void gnf_kernel(
    const float* __restrict__ coords,     // (B, A, 3) f32
    const int*   __restrict__ atom_types, // (B, A) i32
    const float* __restrict__ query,      // (B, P, 3) f32
    float*       __restrict__ out)        // (B, P, 5, 3) f32
{
    __shared__ float4 s_atoms[A_DIM];     // type-sorted (x,y,z,-)
    __shared__ int s_cnt[NT];
    __shared__ int s_seg[NT + 1];
    __shared__ int s_cur[NT];

    const int tid = threadIdx.x;
    const int b   = blockIdx.x >> 8;                  // 256 blocks per batch
    const int p0  = (blockIdx.x & 255) * PTS_PER_BLOCK;

    // group/lane decomposition: 8 lanes per point
    const int k = tid & (KSPLIT - 1);
    const int p = p0 + (tid >> 3);

    // hoist the query load so its VMEM latency hides under the sort preamble
    const float* q = query + (size_t)(b * P_DIM + p) * 3;
    const float qx = q[0], qy = q[1], qz = q[2];

    // ---- count-sort atoms by type into LDS segments ----
    if (tid < NT) s_cnt[tid] = 0;
    __syncthreads();

    float ax = 0.f, ay = 0.f, az = 0.f;
    int ty = -1;
    if (tid < A_DIM) {
        const float* c = coords + (size_t)(b * A_DIM + tid) * 3;
        ax = c[0]; ay = c[1]; az = c[2];
        int t = atom_types[b * A_DIM + tid];
        if (t >= 0 && t < NT) { ty = t; atomicAdd(&s_cnt[t], 1); }
    }
    __syncthreads();
    if (tid == 0) {
        int run = 0;
#pragma unroll
        for (int t = 0; t < NT; ++t) { s_seg[t] = run; s_cur[t] = run; run += s_cnt[t]; }
        s_seg[NT] = run;
    }
    __syncthreads();
    if (ty >= 0) {
        int pos = atomicAdd(&s_cur[ty], 1);
        s_atoms[pos] = make_float4(ax, ay, az, 0.f);
    }
    __syncthreads();

    int seg[NT + 1];
#pragma unroll
    for (int t = 0; t <= NT; ++t) seg[t] = s_seg[t];

    // ---- main: per type, strided over the 8-lane group ----
    float ox = 0.f, oy = 0.f, oz = 0.f;   // this lane's output (type == k)
#pragma unroll
    for (int t = 0; t < NT; ++t) {
        float s = 0.f, gx = 0.f, gy = 0.f, gz = 0.f;
        for (int i = seg[t] + k; i < seg[t + 1]; i += KSPLIT) {
            const float4 at = s_atoms[i];       // 8 consecutive float4 / group
            const float dx = at.x - qx;
            const float dy = at.y - qy;
            const float dz = at.z - qz;
            const float d2 = fmaf(dx, dx, fmaf(dy, dy, dz * dz));
            const float e  = __builtin_amdgcn_exp2f(
                __builtin_amdgcn_sqrtf(d2) * -1.44269504088896340736f);
            s += e;
            gx = fmaf(e, dx, gx);
            gy = fmaf(e, dy, gy);
            gz = fmaf(e, dz, gz);
        }
        // butterfly across the 8-lane group: all 8 lanes get totals
        s  += __shfl_xor(s, 1);  s  += __shfl_xor(s, 2);  s  += __shfl_xor(s, 4);
        gx += __shfl_xor(gx, 1); gx += __shfl_xor(gx, 2); gx += __shfl_xor(gx, 4);
        gy += __shfl_xor(gy, 1); gy += __shfl_xor(gy, 2); gy += __shfl_xor(gy, 4);
        gz += __shfl_xor(gz, 1); gz += __shfl_xor(gz, 2); gz += __shfl_xor(gz, 4);

        if (k == t) {   // lane t of each group owns type t's epilogue
            const float inv = (s > 0.f) ? __builtin_amdgcn_rcpf(s) : 0.0f;
            float x = gx * inv, y = gy * inv, z = gz * inv;
            const float m2 = fmaf(x, x, fmaf(y, y, z * z));
            if (m2 > 0.09f) {                       // mag > 0.3
                const float sc = 0.3f * __builtin_amdgcn_rsqf(m2);
                x *= sc; y *= sc; z *= sc;
            }
            ox = x; oy = y; oz = z;
        }
    }

    // lanes 0..4 store their type's 3 floats (15 per point, contiguous 60B)
    if (k < NT) {
        float* o = out + (size_t)(b * P_DIM + p) * (NT * 3) + k * 3;
        o[0] = ox; o[1] = oy; o[2] = oz;
    }
}

extern "C" void kernel_launch(void* const* d_in, const int* in_sizes, int n_in,
                              void* d_out, int out_size, void* d_ws, size_t ws_size,
                              hipStream_t stream) {
    const float* coords     = (const float*)d_in[0];
    const int*   atom_types = (const int*)d_in[1];
    const float* query      = (const float*)d_in[2];
    float*       out        = (float*)d_out;

    const int nblocks = (B_DIM * P_DIM) / PTS_PER_BLOCK;  // 2048
    gnf_kernel<<<nblocks, 256, 0, stream>>>(coords, atom_types, query, out);
}

// Round 5
// 15.369 us; speedup vs baseline: 1.3333x; 1.0115x over previous
//
#include <hip/hip_runtime.h>

// GNFConverter: per (b,p) point, per-type softmax over atoms of -dist logits,
// weighted sum of (coord - query) diffs, clipped to magnitude 0.3.
// Shapes fixed: B=8, A=128, P=8192, T=5.
//
// Structure (R4 + leaner preamble):
//   - count-sort atoms by type into LDS segments once per block
//     (3 barriers: init, count, scatter; prefix sums computed per-thread in
//     registers — no serial tid==0 section, no s_seg LDS array)
//   - each point handled by an 8-lane group (KSPLIT=8); inner loops run
//     type-by-type over sorted segments: 4 accumulators, no predication
//   - 2048 blocks -> 8 waves/SIMD: ds_read+chain latency fully hidden by TLP
//   - butterfly (xor 1,2,4) reduce within the 8-lane group; lane k==t
//     normalizes+clips type t; lanes 0..4 store 3 dwords each

#define B_DIM 8
#define A_DIM 128
#define P_DIM 8192
#define NT 5
#define KSPLIT 8
#define PTS_PER_BLOCK 32   // 256 threads / KSPLIT

__global__ __launch_bounds__(256) void gnf_kernel(
    const float* __restrict__ coords,     // (B, A, 3) f32
    const int*   __restrict__ atom_types, // (B, A) i32
    const float* __restrict__ query,      // (B, P, 3) f32
    float*       __restrict__ out)        // (B, P, 5, 3) f32
{
    __shared__ float4 s_atoms[A_DIM];     // type-sorted (x,y,z,-)
    __shared__ int s_cnt[NT];
    __shared__ int s_cur[NT];

    const int tid = threadIdx.x;
    const int b   = blockIdx.x >> 8;                  // 256 blocks per batch
    const int p0  = (blockIdx.x & 255) * PTS_PER_BLOCK;

    // 8 lanes per point
    const int k = tid & (KSPLIT - 1);
    const int p = p0 + (tid >> 3);

    // hoist the query load: VMEM latency hides under the sort preamble
    const float* q = query + (size_t)(b * P_DIM + p) * 3;
    const float qx = q[0], qy = q[1], qz = q[2];

    // ---- count-sort atoms by type into LDS segments (3 barriers) ----
    if (tid < NT) { s_cnt[tid] = 0; s_cur[tid] = 0; }
    __syncthreads();

    float ax = 0.f, ay = 0.f, az = 0.f;
    int ty = -1;
    if (tid < A_DIM) {
        const float* c = coords + (size_t)(b * A_DIM + tid) * 3;
        ax = c[0]; ay = c[1]; az = c[2];
        int t = atom_types[b * A_DIM + tid];
        if (t >= 0 && t < NT) { ty = t; atomicAdd(&s_cnt[t], 1); }
    }
    __syncthreads();

    // every thread reads the 5 counts; prefix sums stay in registers
    const int c0 = s_cnt[0], c1 = s_cnt[1], c2 = s_cnt[2], c3 = s_cnt[3], c4 = s_cnt[4];
    int seg[NT + 1];
    seg[0] = 0; seg[1] = c0; seg[2] = seg[1] + c1; seg[3] = seg[2] + c2;
    seg[4] = seg[3] + c3; seg[5] = seg[4] + c4;

    if (ty >= 0) {
        // base = prefix[ty] via select-sum (no runtime-indexed register array)
        int base = (ty > 0 ? c0 : 0) + (ty > 1 ? c1 : 0)
                 + (ty > 2 ? c2 : 0) + (ty > 3 ? c3 : 0);
        int pos = base + atomicAdd(&s_cur[ty], 1);
        s_atoms[pos] = make_float4(ax, ay, az, 0.f);
    }
    __syncthreads();

    // ---- main: per type, strided over the 8-lane group ----
    float ox = 0.f, oy = 0.f, oz = 0.f;   // this lane's output (type == k)
#pragma unroll
    for (int t = 0; t < NT; ++t) {
        float s = 0.f, gx = 0.f, gy = 0.f, gz = 0.f;
        for (int i = seg[t] + k; i < seg[t + 1]; i += KSPLIT) {
            const float4 at = s_atoms[i];       // 8 consecutive float4 / group
            const float dx = at.x - qx;
            const float dy = at.y - qy;
            const float dz = at.z - qz;
            const float d2 = fmaf(dx, dx, fmaf(dy, dy, dz * dz));
            const float e  = __builtin_amdgcn_exp2f(
                __builtin_amdgcn_sqrtf(d2) * -1.44269504088896340736f);
            s += e;
            gx = fmaf(e, dx, gx);
            gy = fmaf(e, dy, gy);
            gz = fmaf(e, dz, gz);
        }
        // butterfly across the 8-lane group: all 8 lanes get totals
        s  += __shfl_xor(s, 1);  s  += __shfl_xor(s, 2);  s  += __shfl_xor(s, 4);
        gx += __shfl_xor(gx, 1); gx += __shfl_xor(gx, 2); gx += __shfl_xor(gx, 4);
        gy += __shfl_xor(gy, 1); gy += __shfl_xor(gy, 2); gy += __shfl_xor(gy, 4);
        gz += __shfl_xor(gz, 1); gz += __shfl_xor(gz, 2); gz += __shfl_xor(gz, 4);

        if (k == t) {   // lane t of each group owns type t's epilogue
            const float inv = (s > 0.f) ? __builtin_amdgcn_rcpf(s) : 0.0f;
            float x = gx * inv, y = gy * inv, z = gz * inv;
            const float m2 = fmaf(x, x, fmaf(y, y, z * z));
            if (m2 > 0.09f) {                       // mag > 0.3
                const float sc = 0.3f * __builtin_amdgcn_rsqf(m2);
                x *= sc; y *= sc; z *= sc;
            }
            ox = x; oy = y; oz = z;
        }
    }

    // lanes 0..4 store their type's 3 floats (15 per point)
    if (k < NT) {
        float* o = out + (size_t)(b * P_DIM + p) * (NT * 3) + k * 3;
        o[0] = ox; o[1] = oy; o[2] = oz;
    }
}

extern "C" void kernel_launch(void* const* d_in, const int* in_sizes, int n_in,
                              void* d_out, int out_size, void* d_ws, size_t ws_size,
                              hipStream_t stream) {
    const float* coords     = (const float*)d_in[0];
    const int*   atom_types = (const int*)d_in[1];
    const float* query      = (const float*)d_in[2];
    float*       out        = (float*)d_out;

    const int nblocks = (B_DIM * P_DIM) / PTS_PER_BLOCK;  // 2048
    gnf_kernel<<<nblocks, 256, 0, stream>>>(coords, atom_types, query, out);
}